// Round 1
// baseline (271.447 us; speedup 1.0000x reference)
//
#include <hip/hip_runtime.h>
#include <math.h>

// Problem constants
#define BB 8
#define HH 1024
#define WW 1024
#define HW (1024*1024)

#define TW 128        // tile width (output px)
#define TH 16         // tile height
#define HALO_H (TH+6) // 22
#define TSTRIDE 136   // tile row stride (bytes); stored col s holds gx = x0-4+s,
                      // so center px gx=x0+x sits at stored col x+4 (u32-aligned)
#define NCOPY 32
#define NSLOT 18      // per image: [0]=focal sum, [1]=edge sum, [2+b]=I_b, [10+b]=U_b
// acc layout: acc[(img*NSLOT + slot)*NCOPY + copy]

__global__ __launch_bounds__(256, 8)
void loss_main(const float* __restrict__ pred,
               const float* __restrict__ diss,
               const int*   __restrict__ target,
               double*      __restrict__ acc)
{
    // target/count data is in {0..29}: store as bytes. Total LDS ~8.8 KB
    // -> occupancy limited by wave slots (8 blocks/CU), not LDS (was 34.8 KB -> 4/CU).
    __shared__ __align__(16) unsigned char tile[HALO_H][TSTRIDE]; // 2992 B
    __shared__ __align__(16) unsigned char h5[HALO_H][TW];        // 2816 B: 5-wide row sums
    __shared__ __align__(16) unsigned char h7[HALO_H][TW];        // 2816 B: 7-wide row sums
    __shared__ float red[4][12];

    const int bx = blockIdx.x;   // 0..7
    const int by = blockIdx.y;   // 0..63
    const int b  = blockIdx.z;   // 0..7
    const int x0 = bx * TW, y0 = by * TH;
    const int tid = threadIdx.x;       // 0..255
    const int txx = tid & 31;          // x-group (4 px each)
    const int ty  = tid >> 5;          // 0..7

    // ---- stage 1: target halo -> LDS bytes (packed u32 per 4 px) ----
    // chunk m of row r covers gx = x0-4+4m .. +3 -> stored cols 4m..4m+3
    const int* tgt_b = target + (size_t)b * HW;
    for (int ch = tid; ch < HALO_H * 34; ch += 256) {
        int r = ch / 34;
        int m = ch - r * 34;
        int gy  = y0 - 3 + r;
        int gxb = x0 - 4 + 4 * m;
        unsigned v = 0u;
        if (gy >= 0 && gy < HH) {
            if (gxb >= 0 && gxb + 3 < WW) {
                const int4 iv = *(const int4*)(tgt_b + (size_t)gy * WW + gxb);
                v = (unsigned)(iv.x & 0xff)
                  | ((unsigned)(iv.y & 0xff) << 8)
                  | ((unsigned)(iv.z & 0xff) << 16)
                  | ((unsigned)(iv.w & 0xff) << 24);
            } else {
                #pragma unroll
                for (int j = 0; j < 4; ++j) {
                    int gx = gxb + j;
                    if (gx >= 0 && gx < WW)
                        v |= (unsigned)(tgt_b[(size_t)gy * WW + gx] & 0xff) << (8 * j);
                }
            }
        }
        *(unsigned*)&tile[r][4 * m] = v;
    }
    __syncthreads();

    // ---- stage 2: horizontal sums, SWAR on packed bytes (no carry: max 7 < 256) ----
    // h5[r][x] = stored cols x+2..x+6 ; h7[r][x] = stored cols x+1..x+7
    for (int g = tid; g < HALO_H * 32; g += 256) {
        int r  = g >> 5;
        int xg = (g & 31) << 2;
        unsigned c0 = *(const unsigned*)&tile[r][xg];       // stored x..x+3
        unsigned c1 = *(const unsigned*)&tile[r][xg + 4];   // x+4..x+7
        unsigned c2 = *(const unsigned*)&tile[r][xg + 8];   // x+8..x+11
        unsigned A1 = (c0 >> 8)  | (c1 << 24);  // P(x+1)
        unsigned A2 = (c0 >> 16) | (c1 << 16);  // P(x+2)
        unsigned A3 = (c0 >> 24) | (c1 << 8);   // P(x+3)
        unsigned A5 = (c1 >> 8)  | (c2 << 24);  // P(x+5)
        unsigned A6 = (c1 >> 16) | (c2 << 16);  // P(x+6)
        unsigned A7 = (c1 >> 24) | (c2 << 8);   // P(x+7)
        unsigned v5 = A2 + A3 + c1 + A5 + A6;   // bytes <= 5
        unsigned v7 = v5 + A1 + A7;             // bytes <= 7
        *(unsigned*)&h5[r][xg] = v5;
        *(unsigned*)&h7[r][xg] = v7;
    }
    __syncthreads();

    // ---- stage 3: fused per-pixel terms, 4 px/thread, 3 images ----
    const float* p00 = pred + ((size_t)(0 * BB + b) * 2 + 0) * HW;
    const float* p01 = p00 + HW;
    const float* p10 = pred + ((size_t)(1 * BB + b) * 2 + 0) * HW;
    const float* p11 = p10 + HW;
    const float* q0  = diss + ((size_t)b * 2 + 0) * HW;
    const float* q1  = q0 + HW;

    float sf0=0.f, se0=0.f, si0=0.f, su0=0.f;
    float sf1=0.f, se1=0.f, si1=0.f, su1=0.f;
    float sf2=0.f, se2=0.f, si2=0.f, su2=0.f;

    const int x  = txx * 4;
    const int gx = x0 + x;
    #pragma unroll
    for (int k = 0; k < 2; ++k) {
        const int r  = ty + 8 * k;       // 0..15
        const int gy = y0 + r;
        const size_t off = (size_t)gy * WW + gx;

        // packed 29-neighbor count: bytes <= 29, no carry across bytes
        const unsigned t4   = *(const unsigned*)&tile[r + 3][x + 4];
        const unsigned cnt4 = *(const unsigned*)&tile[r    ][x + 4]   // dy=-3, width 1
                            + *(const unsigned*)&tile[r + 6][x + 4]   // dy=+3, width 1
                            + *(const unsigned*)&h5[r + 1][x]         // dy=-2, width 5
                            + *(const unsigned*)&h5[r + 2][x]         // dy=-1, width 5
                            + *(const unsigned*)&h7[r + 3][x]         // dy= 0, width 7
                            + *(const unsigned*)&h5[r + 4][x]         // dy=+1, width 5
                            + *(const unsigned*)&h5[r + 5][x];        // dy=+2, width 5

        float4 v00 = *(const float4*)(p00 + off);
        float4 v01 = *(const float4*)(p01 + off);
        float4 v10 = *(const float4*)(p10 + off);
        float4 v11 = *(const float4*)(p11 + off);
        float4 w0  = *(const float4*)(q0  + off);
        float4 w1  = *(const float4*)(q1  + off);

        #pragma unroll
        for (int j = 0; j < 4; ++j) {
            const unsigned tb = (t4 >> (8 * j)) & 0xffu;
            const float t  = (float)tb;
            const float at = fabsf(t - (float)((cnt4 >> (8 * j)) & 0xffu) * (1.0f / 29.0f));
            // image 0 (softmax of 2 channels)
            {
                float a0 = ((const float*)&v00)[j], a1 = ((const float*)&v01)[j];
                float p1v = __builtin_amdgcn_rcpf(1.0f + __expf(a0 - a1));
                float pt  = (tb != 0u) ? p1v : 1.0f - p1v;
                float lp  = __logf(pt + 1e-10f);
                sf0 -= lp; se0 -= lp * at; si0 += p1v * t; su0 += p1v + t;
            }
            // image 1
            {
                float a0 = ((const float*)&v10)[j], a1 = ((const float*)&v11)[j];
                float p1v = __builtin_amdgcn_rcpf(1.0f + __expf(a0 - a1));
                float pt  = (tb != 0u) ? p1v : 1.0f - p1v;
                float lp  = __logf(pt + 1e-10f);
                sf1 -= lp; se1 -= lp * at; si1 += p1v * t; su1 += p1v + t;
            }
            // Diss (raw probs)
            {
                float d0 = ((const float*)&w0)[j], d1 = ((const float*)&w1)[j];
                float pt = (tb != 0u) ? d1 : d0;
                float lp = __logf(pt + 1e-10f);
                sf2 -= lp; se2 -= lp * at; si2 += d1 * t; su2 += d1 + t;
            }
        }
    }

    // ---- stage 4: block reduction -> 12 f64 atomics ----
    float vals[12] = {sf0,se0,si0,su0, sf1,se1,si1,su1, sf2,se2,si2,su2};
    #pragma unroll
    for (int j = 0; j < 12; ++j) {
        float v = vals[j];
        #pragma unroll
        for (int s = 32; s > 0; s >>= 1) v += __shfl_down(v, s, 64);
        vals[j] = v;
    }
    const int wave = tid >> 6;
    const int lane = tid & 63;
    if (lane == 0) {
        #pragma unroll
        for (int j = 0; j < 12; ++j) red[wave][j] = vals[j];
    }
    __syncthreads();
    if (tid < 12) {
        double s = (double)red[0][tid] + (double)red[1][tid]
                 + (double)red[2][tid] + (double)red[3][tid];
        const int img  = tid >> 2;
        const int what = tid & 3;
        int slot;
        if      (what == 0) slot = 0;
        else if (what == 1) slot = 1;
        else if (what == 2) slot = 2 + b;
        else                slot = 10 + b;
        const int copy = (by * 8 + bx) & (NCOPY - 1);
        unsafeAtomicAdd(acc + ((size_t)(img * NSLOT + slot) * NCOPY + copy), s);
    }
}

__global__ __launch_bounds__(256)
void finalize_kernel(const double* __restrict__ acc,
                     const float*  __restrict__ diff,
                     const float*  __restrict__ sigma,
                     float*        __restrict__ out)
{
    __shared__ double ssum[54];
    const int t = threadIdx.x;
    if (t < 216) {
        const int slot_lin = t >> 2;   // 0..53 = img*18+slot
        const int part     = t & 3;
        const double* p = acc + (size_t)slot_lin * NCOPY + part * 8;
        double s = 0.0;
        #pragma unroll
        for (int j = 0; j < 8; ++j) s += p[j];
        s += __shfl_down(s, 1, 64);
        s += __shfl_down(s, 2, 64);
        if (part == 0) ssum[slot_lin] = s;
    }
    __syncthreads();
    if (t == 0) {
        const double sig0 = (double)sigma[0] * (double)sigma[0];
        const double sig1 = (double)sigma[1] * (double)sigma[1];
        const double sig2 = (double)sigma[2] * (double)sigma[2];
        const double inv  = 1.0 / (double)((size_t)BB * HW);
        double loss = 0.0;
        for (int i = 0; i < 3; ++i) {
            const double* A = ssum + i * NSLOT;
            double focal = A[0] * inv;
            double edge  = A[1] * inv;
            double dsum  = 0.0;
            for (int b = 0; b < BB; ++b)
                dsum += 2.0 * A[2 + b] / (A[10 + b] + 1e-10);
            double dice = 1.0 - dsum / (double)BB;
            loss += focal / sig0 + dice / sig1 + edge / sig2;
        }
        loss += (double)diff[0];
        loss += 0.5 * (log(sig0) + log(sig1) + log(sig2));
        out[0] = (float)loss;
    }
}

extern "C" void kernel_launch(void* const* d_in, const int* in_sizes, int n_in,
                              void* d_out, int out_size, void* d_ws, size_t ws_size,
                              hipStream_t stream)
{
    const float* pred   = (const float*)d_in[0]; // (2,8,2,1024,1024)
    const float* diss   = (const float*)d_in[1]; // (1,8,2,1024,1024)
    const int*   target = (const int*)  d_in[2]; // (8,1024,1024)
    const float* diff   = (const float*)d_in[3];
    const float* sigma  = (const float*)d_in[4];
    double* acc = (double*)d_ws;

    hipMemsetAsync(d_ws, 0, (size_t)3 * NSLOT * NCOPY * sizeof(double), stream);

    dim3 grid(WW / TW, HH / TH, BB);   // (8, 64, 8)
    loss_main<<<grid, 256, 0, stream>>>(pred, diss, target, acc);
    finalize_kernel<<<1, 256, 0, stream>>>(acc, diff, sigma, (float*)d_out);
}